// Round 4
// baseline (296.658 us; speedup 1.0000x reference)
//
#include <hip/hip_runtime.h>
#include <math.h>

#define B   16
#define M   1024
#define W   256
#define H   8
#define NW  2
#define NR  4
#define EPSF 1e-6f

typedef float v4f __attribute__((ext_vector_type(4)));

// ---------------------------------------------------------------------------
// Kernel 1: fused mega kernel (round-0 structure, reordered memory issue).
// 4096 blocks x 256 threads. Each wave: one (b,m) memory row. Each block also
// copies a 32 KB slice of the link passthrough.
// Ordering fix vs round 0: vmcnt retires IN ISSUE ORDER, so compute inputs
// (x, k, e, v) are issued BEFORE the 8 link-copy loads. The first compute
// vmcnt-wait then leaves all 8 copy loads in flight; they stream in under
// ~1700 cycles of shuffle/FMA work and are drained at the very end.
// All loads are plain (cached) — nt hints kept only on pure-stream stores.
// ---------------------------------------------------------------------------
__global__ void __launch_bounds__(256) mega_kernel(
    const float* __restrict__ memory, const float* __restrict__ keys,
    const float* __restrict__ ww,     const float* __restrict__ prev_link,
    const float* __restrict__ ev,     const float* __restrict__ wv,
    float* __restrict__ out_mem,      float* __restrict__ out_cos,
    float* __restrict__ out_link,     float* __restrict__ ws_norm) {
    int blk = blockIdx.x;
    int t = threadIdx.x;
    int lane = t & 63;
    int wid = t >> 6;
    int bm = blk * 4 + wid;                        // [0, 16384)
    int b = bm >> 10;
    int m = bm & 1023;

    // ---- 1. compute-input loads first ------------------------------------
    v4f x = ((const v4f*)memory)[(size_t)bm * (W / 4) + lane];
    const v4f* kb = (const v4f*)(keys) + (size_t)b * H * (W / 4);
    v4f k[H];
    #pragma unroll
    for (int h = 0; h < H; ++h) k[h] = kb[h * (W / 4) + lane];

    float w0 = ww[(b * NW + 0) * M + m];
    float w1 = ww[(b * NW + 1) * M + m];
    const v4f* e0p = (const v4f*)(ev) + (size_t)(b * NW) * (W / 4);
    const v4f* v0p = (const v4f*)(wv) + (size_t)(b * NW) * (W / 4);
    v4f e0 = e0p[lane], e1 = e0p[(W / 4) + lane];
    v4f v0 = v0p[lane], v1 = v0p[(W / 4) + lane];

    // ---- 2. issue link-copy loads (8 outstanding, plain) -----------------
    const v4f* s4 = (const v4f*)prev_link;
    v4f* d4 = (v4f*)out_link;
    size_t ci = (size_t)blk * 256 + t;
    const size_t cs = (size_t)4096 * 256;
    v4f cv[8];
    #pragma unroll
    for (int u = 0; u < 8; ++u) cv[u] = s4[ci + u * cs];
    // pin: copy loads must be issued here, not sunk past the compute
    __builtin_amdgcn_sched_barrier(0);

    // ---- 3. compute (waits only on x/k/e/v; copy stays in flight) --------
    float acc[9];
    acc[8] = x.x * x.x + x.y * x.y + x.z * x.z + x.w * x.w;
    #pragma unroll
    for (int h = 0; h < H; ++h)
        acc[h] = x.x * k[h].x + x.y * k[h].y + x.z * k[h].z + x.w * k[h].w;

    #pragma unroll
    for (int off = 1; off < 64; off <<= 1) {
        #pragma unroll
        for (int j = 0; j < 9; ++j) acc[j] += __shfl_xor(acc[j], off);
    }

    v4f r;
    {
        float e;
        e = fminf(fmaxf(w0 * e0.x + w1 * e1.x, 0.f), 1.f);
        r.x = x.x * (1.f - e) + w0 * v0.x + w1 * v1.x;
        e = fminf(fmaxf(w0 * e0.y + w1 * e1.y, 0.f), 1.f);
        r.y = x.y * (1.f - e) + w0 * v0.y + w1 * v1.y;
        e = fminf(fmaxf(w0 * e0.z + w1 * e1.z, 0.f), 1.f);
        r.z = x.z * (1.f - e) + w0 * v0.z + w1 * v1.z;
        e = fminf(fmaxf(w0 * e0.w + w1 * e1.w, 0.f), 1.f);
        r.w = x.w * (1.f - e) + w0 * v0.w + w1 * v1.w;
    }
    __builtin_nontemporal_store(r,
        ((v4f*)out_mem) + (size_t)bm * (W / 4) + lane);

    if (lane < H) {
        float d = acc[0];
        #pragma unroll
        for (int h = 1; h < H; ++h)
            if (lane == h) d = acc[h];
        out_cos[(size_t)(b * H + lane) * M + m] = d;
    }
    if (lane == 0) ws_norm[bm] = sqrtf(acc[8] + EPSF);

    // ---- 4. drain link copy ----------------------------------------------
    #pragma unroll
    for (int u = 0; u < 8; ++u)
        __builtin_nontemporal_store(cv[u], &d4[ci + u * cs]);
}

// ---------------------------------------------------------------------------
// Kernel 2: [0,128) softmax+cosine per (b,h) | [128,144) misc | [144,176) prec
// ---------------------------------------------------------------------------
__global__ void __launch_bounds__(256) finish_kernel(
    const float* __restrict__ keys, const float* __restrict__ strengths,
    const float* __restrict__ ws_norm, const float* __restrict__ ww,
    const float* __restrict__ fg,   const float* __restrict__ rw,
    const float* __restrict__ pu,   const float* __restrict__ rv,
    float* __restrict__ cosr,       float* __restrict__ out_prec,
    float* __restrict__ out_usage,  float* __restrict__ out_read) {
    int blk = blockIdx.x;
    int t = threadIdx.x;
    int wid = t >> 6;

    if (blk < B * H) {
        int bh = blk;
        int b = bh >> 3;
        __shared__ float skn[4];
        __shared__ float sm[4];
        __shared__ float ss[4];

        float kv = keys[(size_t)bh * W + t];
        float s = kv * kv;
        #pragma unroll
        for (int off = 1; off < 64; off <<= 1) s += __shfl_xor(s, off);
        if ((t & 63) == 0) skn[wid] = s;
        __syncthreads();
        float kn = sqrtf(skn[0] + skn[1] + skn[2] + skn[3] + EPSF);
        float sp = log1pf(expf(strengths[bh]));

        float* row = cosr + (size_t)bh * M;
        float v[4];
        #pragma unroll
        for (int c = 0; c < 4; ++c) {
            int m = t + c * 256;
            float d = row[m];
            float nm = ws_norm[b * M + m];
            v[c] = d / (nm * kn + EPSF) * sp;
        }

        float mx = fmaxf(fmaxf(v[0], v[1]), fmaxf(v[2], v[3]));
        #pragma unroll
        for (int off = 1; off < 64; off <<= 1) mx = fmaxf(mx, __shfl_xor(mx, off));
        if ((t & 63) == 0) sm[wid] = mx;
        __syncthreads();
        mx = fmaxf(fmaxf(sm[0], sm[1]), fmaxf(sm[2], sm[3]));

        float sum = 0.f;
        #pragma unroll
        for (int c = 0; c < 4; ++c) { v[c] = expf(v[c] - mx); sum += v[c]; }
        #pragma unroll
        for (int off = 1; off < 64; off <<= 1) sum += __shfl_xor(sum, off);
        if ((t & 63) == 0) ss[wid] = sum;
        __syncthreads();
        float inv = 1.f / (ss[0] + ss[1] + ss[2] + ss[3]);

        #pragma unroll
        for (int c = 0; c < 4; ++c) row[t + c * 256] = v[c] * inv;
        return;
    }

    if (blk < B * H + B) {
        int b = blk - B * H;
        __shared__ float spm[4][NR];

        float f[NR];
        #pragma unroll
        for (int n = 0; n < NR; ++n) f[n] = fg[b * NR + n];

        float part[NR] = {0.f, 0.f, 0.f, 0.f};
        #pragma unroll
        for (int c = 0; c < 4; ++c) {
            int m = t + c * 256;
            float u = pu[b * M + m] + ww[(b * NW + 0) * M + m]
                                    + ww[(b * NW + 1) * M + m];
            #pragma unroll
            for (int n = 0; n < NR; ++n) {
                float r = rw[(size_t)(b * NR + n) * M + m];
                part[n] += r;
                u -= r * f[n];
            }
            out_usage[b * M + m] = fminf(fmaxf(u, 0.f), 1.f);
        }

        #pragma unroll
        for (int off = 1; off < 64; off <<= 1) {
            #pragma unroll
            for (int n = 0; n < NR; ++n) part[n] += __shfl_xor(part[n], off);
        }
        if ((t & 63) == 0) {
            #pragma unroll
            for (int n = 0; n < NR; ++n) spm[wid][n] = part[n];
        }
        __syncthreads();

        float ro = 0.f;
        #pragma unroll
        for (int n = 0; n < NR; ++n) {
            float rs = spm[0][n] + spm[1][n] + spm[2][n] + spm[3][n];
            ro += rs * rv[(size_t)(b * NR + n) * W + t];
        }
        out_read[b * W + t] = ro;
        return;
    }

    {
        int i = (blk - (B * H + B)) * 256 + t;     // [0, 8192)
        ((v4f*)out_prec)[i] = ((const v4f*)ww)[i];
    }
}

// ---------------------------------------------------------------------------
extern "C" void kernel_launch(void* const* d_in, const int* in_sizes, int n_in,
                              void* d_out, int out_size, void* d_ws, size_t ws_size,
                              hipStream_t stream) {
    const float* memory        = (const float*)d_in[0];
    const float* keys          = (const float*)d_in[1];
    const float* strengths     = (const float*)d_in[2];
    const float* write_weights = (const float*)d_in[3];
    const float* free_gate     = (const float*)d_in[4];
    const float* read_weights  = (const float*)d_in[5];
    const float* prev_link     = (const float*)d_in[6];
    const float* prev_usage    = (const float*)d_in[8];
    const float* erase_vectors = (const float*)d_in[9];
    const float* write_vectors = (const float*)d_in[10];
    const float* read_vectors  = (const float*)d_in[11];

    float* out = (float*)d_out;
    float* out_mem   = out;                       // [B,M,W]     4,194,304
    float* out_cos   = out + 4194304;             // [B,H,M]       131,072
    float* out_link  = out + 4325376;             // [B,NW,M,M] 33,554,432
    float* out_prec  = out + 37879808;            // [B,NW,M]       32,768
    float* out_usage = out + 37912576;            // [B,M]          16,384
    float* out_read  = out + 37928960;            // [B,W]           4,096

    float* ws_norm = (float*)d_ws;                // [B*M] = 16,384 floats

    hipLaunchKernelGGL(mega_kernel, dim3(4096), dim3(256), 0, stream,
                       memory, keys, write_weights, prev_link,
                       erase_vectors, write_vectors,
                       out_mem, out_cos, out_link, ws_norm);
    hipLaunchKernelGGL(finish_kernel, dim3(B * H + B + 32), dim3(256), 0,
                       stream,
                       keys, strengths, ws_norm, write_weights, free_gate,
                       read_weights, prev_usage, read_vectors,
                       out_cos, out_prec, out_usage, out_read);
}

// Round 5
// 281.039 us; speedup vs baseline: 1.0556x; 1.0556x over previous
//
#include <hip/hip_runtime.h>
#include <math.h>

#define B   16
#define M   1024
#define W   256
#define H   8
#define NW  2
#define NR  4
#define EPSF 1e-6f

typedef float v4f __attribute__((ext_vector_type(4)));

// Kernel 1: 4096 UNIFORM blocks (round-0 best-measured structure, with ALL
// nontemporal hints removed — fill/m13-copy parity: plain cached loads and
// stores so L3 can serve re-reads and absorb the store stream).
//   - 4 waves, one (b,m) memory row each (norm + 8 key dots + erase/write)
//   - a 2048-float4 (32 KB) contiguous slice of the link copy, interleaved
//     so copy-load latency hides under the dot-product VALU work.
#define NBLK_MEGA 4096

__global__ void __launch_bounds__(256) mega_kernel(
    const float* __restrict__ memory, const float* __restrict__ keys,
    const float* __restrict__ ww,     const float* __restrict__ prev_link,
    const float* __restrict__ ev,     const float* __restrict__ wv,
    float* __restrict__ out_mem,      float* __restrict__ out_cos,
    float* __restrict__ out_link,     float* __restrict__ ws_norm) {
    int blk = blockIdx.x;
    int t = threadIdx.x;
    int lane = t & 63;
    int wid = t >> 6;
    int bm = blk * 4 + wid;                        // [0, 16384)
    int b = bm >> 10;
    int m = bm & 1023;

    const v4f* s4 = (const v4f*)prev_link;
    v4f* d4 = (v4f*)out_link;
    int cbase = blk * 2048 + t;

    // ---- copy first half: issue loads, keep in flight --------------------
    v4f cv[4];
    #pragma unroll
    for (int u = 0; u < 4; ++u)
        cv[u] = s4[cbase + u * 256];

    // ---- memory row: load + norm + key dots (hides copy-load latency) ----
    v4f x = ((const v4f*)memory)[(size_t)bm * (W / 4) + lane];

    float acc[9];
    acc[8] = x.x * x.x + x.y * x.y + x.z * x.z + x.w * x.w;
    const v4f* kb = (const v4f*)(keys) + (size_t)b * H * (W / 4);
    #pragma unroll
    for (int h = 0; h < H; ++h) {
        v4f k = kb[h * (W / 4) + lane];
        acc[h] = x.x * k.x + x.y * k.y + x.z * k.z + x.w * k.w;
    }
    #pragma unroll
    for (int off = 1; off < 64; off <<= 1) {
        #pragma unroll
        for (int j = 0; j < 9; ++j) acc[j] += __shfl_xor(acc[j], off);
    }

    // ---- drain copy first half, launch second half -----------------------
    #pragma unroll
    for (int u = 0; u < 4; ++u)
        d4[cbase + u * 256] = cv[u];
    #pragma unroll
    for (int u = 0; u < 4; ++u)
        cv[u] = s4[cbase + (u + 4) * 256];

    // ---- erase / write update (hides second copy-load latency) -----------
    float w0 = ww[(b * NW + 0) * M + m];
    float w1 = ww[(b * NW + 1) * M + m];
    const v4f* e0p = (const v4f*)(ev) + (size_t)(b * NW) * (W / 4);
    const v4f* v0p = (const v4f*)(wv) + (size_t)(b * NW) * (W / 4);
    v4f e0 = e0p[lane], e1 = e0p[(W / 4) + lane];
    v4f v0 = v0p[lane], v1 = v0p[(W / 4) + lane];
    v4f r;
    {
        float e;
        e = fminf(fmaxf(w0 * e0.x + w1 * e1.x, 0.f), 1.f);
        r.x = x.x * (1.f - e) + w0 * v0.x + w1 * v1.x;
        e = fminf(fmaxf(w0 * e0.y + w1 * e1.y, 0.f), 1.f);
        r.y = x.y * (1.f - e) + w0 * v0.y + w1 * v1.y;
        e = fminf(fmaxf(w0 * e0.z + w1 * e1.z, 0.f), 1.f);
        r.z = x.z * (1.f - e) + w0 * v0.z + w1 * v1.z;
        e = fminf(fmaxf(w0 * e0.w + w1 * e1.w, 0.f), 1.f);
        r.w = x.w * (1.f - e) + w0 * v0.w + w1 * v1.w;
    }
    ((v4f*)out_mem)[(size_t)bm * (W / 4) + lane] = r;

    // raw dot per head (cosine scale deferred to kernel 2)
    if (lane < H) {
        float d = acc[0];
        #pragma unroll
        for (int h = 1; h < H; ++h)
            if (lane == h) d = acc[h];
        out_cos[(size_t)(b * H + lane) * M + m] = d;
    }
    if (lane == 0) ws_norm[bm] = sqrtf(acc[8] + EPSF);

    // ---- drain copy second half ------------------------------------------
    #pragma unroll
    for (int u = 0; u < 4; ++u)
        d4[cbase + (u + 4) * 256] = cv[u];
}

// ---------------------------------------------------------------------------
// Kernel 2: [0,128) softmax+cosine per (b,h) | [128,144) misc | [144,176) prec
// ---------------------------------------------------------------------------
__global__ void __launch_bounds__(256) finish_kernel(
    const float* __restrict__ keys, const float* __restrict__ strengths,
    const float* __restrict__ ws_norm, const float* __restrict__ ww,
    const float* __restrict__ fg,   const float* __restrict__ rw,
    const float* __restrict__ pu,   const float* __restrict__ rv,
    float* __restrict__ cosr,       float* __restrict__ out_prec,
    float* __restrict__ out_usage,  float* __restrict__ out_read) {
    int blk = blockIdx.x;
    int t = threadIdx.x;
    int wid = t >> 6;

    if (blk < B * H) {
        int bh = blk;
        int b = bh >> 3;
        __shared__ float skn[4];
        __shared__ float sm[4];
        __shared__ float ss[4];

        float kv = keys[(size_t)bh * W + t];
        float s = kv * kv;
        #pragma unroll
        for (int off = 1; off < 64; off <<= 1) s += __shfl_xor(s, off);
        if ((t & 63) == 0) skn[wid] = s;
        __syncthreads();
        float kn = sqrtf(skn[0] + skn[1] + skn[2] + skn[3] + EPSF);
        float sp = log1pf(expf(strengths[bh]));

        float* row = cosr + (size_t)bh * M;
        float v[4];
        #pragma unroll
        for (int c = 0; c < 4; ++c) {
            int m = t + c * 256;
            float d = row[m];
            float nm = ws_norm[b * M + m];
            v[c] = d / (nm * kn + EPSF) * sp;
        }

        float mx = fmaxf(fmaxf(v[0], v[1]), fmaxf(v[2], v[3]));
        #pragma unroll
        for (int off = 1; off < 64; off <<= 1) mx = fmaxf(mx, __shfl_xor(mx, off));
        if ((t & 63) == 0) sm[wid] = mx;
        __syncthreads();
        mx = fmaxf(fmaxf(sm[0], sm[1]), fmaxf(sm[2], sm[3]));

        float sum = 0.f;
        #pragma unroll
        for (int c = 0; c < 4; ++c) { v[c] = expf(v[c] - mx); sum += v[c]; }
        #pragma unroll
        for (int off = 1; off < 64; off <<= 1) sum += __shfl_xor(sum, off);
        if ((t & 63) == 0) ss[wid] = sum;
        __syncthreads();
        float inv = 1.f / (ss[0] + ss[1] + ss[2] + ss[3]);

        #pragma unroll
        for (int c = 0; c < 4; ++c) row[t + c * 256] = v[c] * inv;
        return;
    }

    if (blk < B * H + B) {
        int b = blk - B * H;
        __shared__ float spm[4][NR];

        float f[NR];
        #pragma unroll
        for (int n = 0; n < NR; ++n) f[n] = fg[b * NR + n];

        float part[NR] = {0.f, 0.f, 0.f, 0.f};
        #pragma unroll
        for (int c = 0; c < 4; ++c) {
            int m = t + c * 256;
            float u = pu[b * M + m] + ww[(b * NW + 0) * M + m]
                                    + ww[(b * NW + 1) * M + m];
            #pragma unroll
            for (int n = 0; n < NR; ++n) {
                float r = rw[(size_t)(b * NR + n) * M + m];
                part[n] += r;
                u -= r * f[n];
            }
            out_usage[b * M + m] = fminf(fmaxf(u, 0.f), 1.f);
        }

        #pragma unroll
        for (int off = 1; off < 64; off <<= 1) {
            #pragma unroll
            for (int n = 0; n < NR; ++n) part[n] += __shfl_xor(part[n], off);
        }
        if ((t & 63) == 0) {
            #pragma unroll
            for (int n = 0; n < NR; ++n) spm[wid][n] = part[n];
        }
        __syncthreads();

        float ro = 0.f;
        #pragma unroll
        for (int n = 0; n < NR; ++n) {
            float rs = spm[0][n] + spm[1][n] + spm[2][n] + spm[3][n];
            ro += rs * rv[(size_t)(b * NR + n) * W + t];
        }
        out_read[b * W + t] = ro;
        return;
    }

    {
        int i = (blk - (B * H + B)) * 256 + t;     // [0, 8192)
        ((v4f*)out_prec)[i] = ((const v4f*)ww)[i];
    }
}

// ---------------------------------------------------------------------------
extern "C" void kernel_launch(void* const* d_in, const int* in_sizes, int n_in,
                              void* d_out, int out_size, void* d_ws, size_t ws_size,
                              hipStream_t stream) {
    const float* memory        = (const float*)d_in[0];
    const float* keys          = (const float*)d_in[1];
    const float* strengths     = (const float*)d_in[2];
    const float* write_weights = (const float*)d_in[3];
    const float* free_gate     = (const float*)d_in[4];
    const float* read_weights  = (const float*)d_in[5];
    const float* prev_link     = (const float*)d_in[6];
    const float* prev_usage    = (const float*)d_in[8];
    const float* erase_vectors = (const float*)d_in[9];
    const float* write_vectors = (const float*)d_in[10];
    const float* read_vectors  = (const float*)d_in[11];

    float* out = (float*)d_out;
    float* out_mem   = out;                       // [B,M,W]     4,194,304
    float* out_cos   = out + 4194304;             // [B,H,M]       131,072
    float* out_link  = out + 4325376;             // [B,NW,M,M] 33,554,432
    float* out_prec  = out + 37879808;            // [B,NW,M]       32,768
    float* out_usage = out + 37912576;            // [B,M]          16,384
    float* out_read  = out + 37928960;            // [B,W]           4,096

    float* ws_norm = (float*)d_ws;                // [B*M] = 16,384 floats

    hipLaunchKernelGGL(mega_kernel, dim3(NBLK_MEGA), dim3(256), 0, stream,
                       memory, keys, write_weights, prev_link,
                       erase_vectors, write_vectors,
                       out_mem, out_cos, out_link, ws_norm);
    hipLaunchKernelGGL(finish_kernel, dim3(B * H + B + 32), dim3(256), 0,
                       stream,
                       keys, strengths, ws_norm, write_weights, free_gate,
                       read_weights, prev_usage, read_vectors,
                       out_cos, out_prec, out_usage, out_read);
}

// Round 6
// 273.475 us; speedup vs baseline: 1.0848x; 1.0277x over previous
//
#include <hip/hip_runtime.h>
#include <math.h>

#define B   16
#define M   1024
#define W   256
#define H   8
#define NW  2
#define NR  4
#define EPSF 1e-6f

// clang native vector type — accepted by __builtin_nontemporal_*
typedef float v4f __attribute__((ext_vector_type(4)));

// Kernel 1: 4096 UNIFORM blocks. Each block:
//   - 4 waves, one (b,m) memory row each (norm + 8 key dots + erase/write)
//   - a 2048-float4 (32 KB) slice of the link copy, interleaved so copy-load
//     latency hides under the dot-product VALU work.
// Best-measured configuration (272.9/274.2 us): 2 graph nodes, nt hints on
// the streaming copy (keeps it out of the L2/L3 working set of the
// concurrently-running harness fills), copy interleaved with the reduction.
#define NBLK_MEGA 4096

__global__ void __launch_bounds__(256) mega_kernel(
    const float* __restrict__ memory, const float* __restrict__ keys,
    const float* __restrict__ ww,     const float* __restrict__ prev_link,
    const float* __restrict__ ev,     const float* __restrict__ wv,
    float* __restrict__ out_mem,      float* __restrict__ out_cos,
    float* __restrict__ out_link,     float* __restrict__ ws_norm) {
    int blk = blockIdx.x;
    int t = threadIdx.x;
    int lane = t & 63;
    int wid = t >> 6;
    int bm = blk * 4 + wid;                        // [0, 16384)
    int b = bm >> 10;
    int m = bm & 1023;

    const v4f* s4 = (const v4f*)prev_link;
    v4f* d4 = (v4f*)out_link;
    int cbase = blk * 2048 + t;

    // ---- copy first half: issue loads, keep in flight --------------------
    v4f cv[4];
    #pragma unroll
    for (int u = 0; u < 4; ++u)
        cv[u] = __builtin_nontemporal_load(&s4[cbase + u * 256]);

    // ---- memory row: load + norm + key dots (hides copy-load latency) ----
    v4f x = __builtin_nontemporal_load(
        ((const v4f*)memory) + (size_t)bm * (W / 4) + lane);

    float acc[9];
    acc[8] = x.x * x.x + x.y * x.y + x.z * x.z + x.w * x.w;
    const v4f* kb = (const v4f*)(keys) + (size_t)b * H * (W / 4);
    #pragma unroll
    for (int h = 0; h < H; ++h) {
        v4f k = kb[h * (W / 4) + lane];
        acc[h] = x.x * k.x + x.y * k.y + x.z * k.z + x.w * k.w;
    }
    #pragma unroll
    for (int off = 1; off < 64; off <<= 1) {
        #pragma unroll
        for (int j = 0; j < 9; ++j) acc[j] += __shfl_xor(acc[j], off);
    }

    // ---- drain copy first half, launch second half -----------------------
    #pragma unroll
    for (int u = 0; u < 4; ++u)
        __builtin_nontemporal_store(cv[u], &d4[cbase + u * 256]);
    #pragma unroll
    for (int u = 0; u < 4; ++u)
        cv[u] = __builtin_nontemporal_load(&s4[cbase + (u + 4) * 256]);

    // ---- erase / write update (hides second copy-load latency) -----------
    float w0 = ww[(b * NW + 0) * M + m];
    float w1 = ww[(b * NW + 1) * M + m];
    const v4f* e0p = (const v4f*)(ev) + (size_t)(b * NW) * (W / 4);
    const v4f* v0p = (const v4f*)(wv) + (size_t)(b * NW) * (W / 4);
    v4f e0 = e0p[lane], e1 = e0p[(W / 4) + lane];
    v4f v0 = v0p[lane], v1 = v0p[(W / 4) + lane];
    v4f r;
    {
        float e;
        e = fminf(fmaxf(w0 * e0.x + w1 * e1.x, 0.f), 1.f);
        r.x = x.x * (1.f - e) + w0 * v0.x + w1 * v1.x;
        e = fminf(fmaxf(w0 * e0.y + w1 * e1.y, 0.f), 1.f);
        r.y = x.y * (1.f - e) + w0 * v0.y + w1 * v1.y;
        e = fminf(fmaxf(w0 * e0.z + w1 * e1.z, 0.f), 1.f);
        r.z = x.z * (1.f - e) + w0 * v0.z + w1 * v1.z;
        e = fminf(fmaxf(w0 * e0.w + w1 * e1.w, 0.f), 1.f);
        r.w = x.w * (1.f - e) + w0 * v0.w + w1 * v1.w;
    }
    __builtin_nontemporal_store(r,
        ((v4f*)out_mem) + (size_t)bm * (W / 4) + lane);

    // raw dot per head (cosine scale deferred to kernel 2)
    if (lane < H) {
        float d = acc[0];
        #pragma unroll
        for (int h = 1; h < H; ++h)
            if (lane == h) d = acc[h];
        out_cos[(size_t)(b * H + lane) * M + m] = d;
    }
    if (lane == 0) ws_norm[bm] = sqrtf(acc[8] + EPSF);

    // ---- drain copy second half ------------------------------------------
    #pragma unroll
    for (int u = 0; u < 4; ++u)
        __builtin_nontemporal_store(cv[u], &d4[cbase + (u + 4) * 256]);
}

// ---------------------------------------------------------------------------
// Kernel 2: [0,128) softmax+cosine per (b,h) | [128,144) misc | [144,176) prec
// ---------------------------------------------------------------------------
__global__ void __launch_bounds__(256) finish_kernel(
    const float* __restrict__ keys, const float* __restrict__ strengths,
    const float* __restrict__ ws_norm, const float* __restrict__ ww,
    const float* __restrict__ fg,   const float* __restrict__ rw,
    const float* __restrict__ pu,   const float* __restrict__ rv,
    float* __restrict__ cosr,       float* __restrict__ out_prec,
    float* __restrict__ out_usage,  float* __restrict__ out_read) {
    int blk = blockIdx.x;
    int t = threadIdx.x;
    int wid = t >> 6;

    if (blk < B * H) {
        // ------------------ softmax + cosine scaling ----------------------
        int bh = blk;
        int b = bh >> 3;
        __shared__ float skn[4];
        __shared__ float sm[4];
        __shared__ float ss[4];

        float kv = keys[(size_t)bh * W + t];
        float s = kv * kv;
        #pragma unroll
        for (int off = 1; off < 64; off <<= 1) s += __shfl_xor(s, off);
        if ((t & 63) == 0) skn[wid] = s;
        __syncthreads();
        float kn = sqrtf(skn[0] + skn[1] + skn[2] + skn[3] + EPSF);
        float sp = log1pf(expf(strengths[bh]));

        float* row = cosr + (size_t)bh * M;
        float v[4];
        #pragma unroll
        for (int c = 0; c < 4; ++c) {
            int m = t + c * 256;
            float d = row[m];
            float nm = ws_norm[b * M + m];
            v[c] = d / (nm * kn + EPSF) * sp;
        }

        float mx = fmaxf(fmaxf(v[0], v[1]), fmaxf(v[2], v[3]));
        #pragma unroll
        for (int off = 1; off < 64; off <<= 1) mx = fmaxf(mx, __shfl_xor(mx, off));
        if ((t & 63) == 0) sm[wid] = mx;
        __syncthreads();
        mx = fmaxf(fmaxf(sm[0], sm[1]), fmaxf(sm[2], sm[3]));

        float sum = 0.f;
        #pragma unroll
        for (int c = 0; c < 4; ++c) { v[c] = expf(v[c] - mx); sum += v[c]; }
        #pragma unroll
        for (int off = 1; off < 64; off <<= 1) sum += __shfl_xor(sum, off);
        if ((t & 63) == 0) ss[wid] = sum;
        __syncthreads();
        float inv = 1.f / (ss[0] + ss[1] + ss[2] + ss[3]);

        #pragma unroll
        for (int c = 0; c < 4; ++c) row[t + c * 256] = v[c] * inv;
        return;
    }

    if (blk < B * H + B) {
        // ------------------ usage + read_output ---------------------------
        int b = blk - B * H;
        __shared__ float spm[4][NR];

        float f[NR];
        #pragma unroll
        for (int n = 0; n < NR; ++n) f[n] = fg[b * NR + n];

        float part[NR] = {0.f, 0.f, 0.f, 0.f};
        #pragma unroll
        for (int c = 0; c < 4; ++c) {
            int m = t + c * 256;
            float u = pu[b * M + m] + ww[(b * NW + 0) * M + m]
                                    + ww[(b * NW + 1) * M + m];
            #pragma unroll
            for (int n = 0; n < NR; ++n) {
                float r = rw[(size_t)(b * NR + n) * M + m];
                part[n] += r;
                u -= r * f[n];
            }
            out_usage[b * M + m] = fminf(fmaxf(u, 0.f), 1.f);
        }

        #pragma unroll
        for (int off = 1; off < 64; off <<= 1) {
            #pragma unroll
            for (int n = 0; n < NR; ++n) part[n] += __shfl_xor(part[n], off);
        }
        if ((t & 63) == 0) {
            #pragma unroll
            for (int n = 0; n < NR; ++n) spm[wid][n] = part[n];
        }
        __syncthreads();

        float ro = 0.f;
        #pragma unroll
        for (int n = 0; n < NR; ++n) {
            float rs = spm[0][n] + spm[1][n] + spm[2][n] + spm[3][n];
            ro += rs * rv[(size_t)(b * NR + n) * W + t];
        }
        out_read[b * W + t] = ro;
        return;
    }

    // ---------------------- precedence := write_weights -------------------
    {
        int i = (blk - (B * H + B)) * 256 + t;     // [0, 8192)
        ((v4f*)out_prec)[i] = ((const v4f*)ww)[i];
    }
}

// ---------------------------------------------------------------------------
extern "C" void kernel_launch(void* const* d_in, const int* in_sizes, int n_in,
                              void* d_out, int out_size, void* d_ws, size_t ws_size,
                              hipStream_t stream) {
    const float* memory        = (const float*)d_in[0];
    const float* keys          = (const float*)d_in[1];
    const float* strengths     = (const float*)d_in[2];
    const float* write_weights = (const float*)d_in[3];
    const float* free_gate     = (const float*)d_in[4];
    const float* read_weights  = (const float*)d_in[5];
    const float* prev_link     = (const float*)d_in[6];
    const float* prev_usage    = (const float*)d_in[8];
    const float* erase_vectors = (const float*)d_in[9];
    const float* write_vectors = (const float*)d_in[10];
    const float* read_vectors  = (const float*)d_in[11];

    float* out = (float*)d_out;
    float* out_mem   = out;                       // [B,M,W]     4,194,304
    float* out_cos   = out + 4194304;             // [B,H,M]       131,072
    float* out_link  = out + 4325376;             // [B,NW,M,M] 33,554,432
    float* out_prec  = out + 37879808;            // [B,NW,M]       32,768
    float* out_usage = out + 37912576;            // [B,M]          16,384
    float* out_read  = out + 37928960;            // [B,W]           4,096

    float* ws_norm = (float*)d_ws;                // [B*M] = 16,384 floats

    hipLaunchKernelGGL(mega_kernel, dim3(NBLK_MEGA), dim3(256), 0, stream,
                       memory, keys, write_weights, prev_link,
                       erase_vectors, write_vectors,
                       out_mem, out_cos, out_link, ws_norm);
    hipLaunchKernelGGL(finish_kernel, dim3(B * H + B + 32), dim3(256), 0,
                       stream,
                       keys, strengths, ws_norm, write_weights, free_gate,
                       read_weights, prev_usage, read_vectors,
                       out_cos, out_prec, out_usage, out_read);
}